// Round 1
// baseline (3063.306 us; speedup 1.0000x reference)
//
#include <hip/hip_runtime.h>
#include <math.h>

#define G 4
#define NN 50000
#define EE 400000
#define D 128
#define LN_EPS 1e-5f

// ---------------- CSR build ----------------

__global__ __launch_bounds__(256) void hist_kernel(const int* __restrict__ ei, int* __restrict__ deg) {
    int idx = blockIdx.x * 256 + threadIdx.x;
    if (idx >= G * EE) return;
    int g = idx / EE, e = idx - g * EE;
    int dst = ei[g * 2 * EE + EE + e];
    atomicAdd(&deg[g * NN + dst], 1);
}

__global__ __launch_bounds__(256) void scan_kernel(const int* __restrict__ deg, int* __restrict__ row_start,
                                                   int* __restrict__ cursor) {
    int g = blockIdx.x, t = threadIdx.x;
    const int C = (NN + 255) / 256;  // 196
    __shared__ int sums[256];
    int start = t * C, end = min(start + C, NN);
    int s = 0;
    for (int i = start; i < end; ++i) s += deg[g * NN + i];
    sums[t] = s;
    __syncthreads();
    for (int off = 1; off < 256; off <<= 1) {
        int v = (t >= off) ? sums[t - off] : 0;
        __syncthreads();
        sums[t] += v;
        __syncthreads();
    }
    int run = (t == 0) ? 0 : sums[t - 1];
    for (int i = start; i < end; ++i) {
        row_start[g * (NN + 1) + i] = run;
        cursor[g * NN + i] = run;
        run += deg[g * NN + i];
    }
    if (t == 255) row_start[g * (NN + 1) + NN] = sums[255];
}

__global__ __launch_bounds__(256) void place_kernel(const int* __restrict__ ei, int* __restrict__ cursor,
                                                    int* __restrict__ csr_src) {
    int idx = blockIdx.x * 256 + threadIdx.x;
    if (idx >= G * EE) return;
    int g = idx / EE, e = idx - g * EE;
    int src = ei[g * 2 * EE + e];
    int dst = ei[g * 2 * EE + EE + e];
    int pos = atomicAdd(&cursor[g * NN + dst], 1);
    csr_src[g * EE + pos] = src;
}

// ---------------- Aggregation: B[n] = X[n] + sum_{j->n} X[j] ----------------

__global__ __launch_bounds__(256) void agg_kernel(const float* __restrict__ X, const int* __restrict__ row_start,
                                                  const int* __restrict__ csr_src, float* __restrict__ B) {
    int idx = blockIdx.x * 8 + (threadIdx.x >> 5);  // node id in [0, G*NN)
    int lane = threadIdx.x & 31;
    int g = idx / NN, n = idx - g * NN;
    const float4* Xv = (const float4*)X;
    float4 acc = Xv[idx * 32 + lane];
    int s0 = row_start[g * (NN + 1) + n];
    int s1 = row_start[g * (NN + 1) + n + 1];
    const int* srcs = csr_src + g * EE;
    int gbase = g * NN * 32;
    for (int k = s0; k < s1; ++k) {
        int sr = srcs[k];
        float4 v = Xv[gbase + sr * 32 + lane];
        acc.x += v.x; acc.y += v.y; acc.z += v.z; acc.w += v.w;
    }
    ((float4*)B)[idx * 32 + lane] = acc;
}

// ---------------- Fused MLP + residual + LayerNorm (+ optional readout) ----------------
// per node: out = LN( relu(h@W1 + b1)@W2 + b2 (+ identity) ) ; gvec[g] += out on last layer

__global__ __launch_bounds__(256) void mlp_kernel(const float* __restrict__ H, const float* __restrict__ Xid,
                                                  float* __restrict__ Out,
                                                  const float* __restrict__ W1, const float* __restrict__ b1,
                                                  const float* __restrict__ W2, const float* __restrict__ b2,
                                                  const float* __restrict__ lng, const float* __restrict__ lnb,
                                                  int has_res, int do_readout, float* __restrict__ gvec) {
    __shared__ float lh[8][128];
    int s = threadIdx.x >> 5;       // node slot 0..7
    int l = threadIdx.x & 31;       // lane in 32-group
    int idx = blockIdx.x * 8 + s;   // node id
    int j = l * 4;

    float4 h = ((const float4*)H)[idx * 32 + l];
    *(float4*)&lh[s][j] = h;
    __syncthreads();

    // y1 = relu(h @ W1 + b1)
    float4 acc = ((const float4*)b1)[l];
#pragma unroll 4
    for (int k = 0; k < 128; ++k) {
        float hk = lh[s][k];
        float4 w = ((const float4*)W1)[k * 32 + l];
        acc.x += hk * w.x; acc.y += hk * w.y; acc.z += hk * w.z; acc.w += hk * w.w;
    }
    acc.x = fmaxf(acc.x, 0.f); acc.y = fmaxf(acc.y, 0.f);
    acc.z = fmaxf(acc.z, 0.f); acc.w = fmaxf(acc.w, 0.f);

    __syncthreads();
    *(float4*)&lh[s][j] = acc;
    __syncthreads();

    // y2 = y1 @ W2 + b2
    float4 acc2 = ((const float4*)b2)[l];
#pragma unroll 4
    for (int k = 0; k < 128; ++k) {
        float yk = lh[s][k];
        float4 w = ((const float4*)W2)[k * 32 + l];
        acc2.x += yk * w.x; acc2.y += yk * w.y; acc2.z += yk * w.z; acc2.w += yk * w.w;
    }

    if (has_res) {
        float4 id = ((const float4*)Xid)[idx * 32 + l];
        acc2.x += id.x; acc2.y += id.y; acc2.z += id.z; acc2.w += id.w;
    }

    // LayerNorm over 128 feats (population var)
    float s1 = acc2.x + acc2.y + acc2.z + acc2.w;
    float s2 = acc2.x * acc2.x + acc2.y * acc2.y + acc2.z * acc2.z + acc2.w * acc2.w;
    for (int off = 16; off > 0; off >>= 1) {
        s1 += __shfl_down(s1, off, 32);
        s2 += __shfl_down(s2, off, 32);
    }
    s1 = __shfl(s1, 0, 32);
    s2 = __shfl(s2, 0, 32);
    float mean = s1 * (1.f / 128.f);
    float var = s2 * (1.f / 128.f) - mean * mean;
    float rstd = rsqrtf(var + LN_EPS);
    float4 gg = ((const float4*)lng)[l];
    float4 bb = ((const float4*)lnb)[l];
    float4 o;
    o.x = (acc2.x - mean) * rstd * gg.x + bb.x;
    o.y = (acc2.y - mean) * rstd * gg.y + bb.y;
    o.z = (acc2.z - mean) * rstd * gg.z + bb.z;
    o.w = (acc2.w - mean) * rstd * gg.w + bb.w;
    ((float4*)Out)[idx * 32 + l] = o;

    if (do_readout) {
        __syncthreads();
        *(float4*)&lh[s][j] = o;
        __syncthreads();
        if (threadIdx.x < 128) {
            float v = 0.f;
#pragma unroll
            for (int q = 0; q < 8; ++q) v += lh[q][threadIdx.x];
            int g = (blockIdx.x * 8) / NN;  // 50000 % 8 == 0, block never straddles graphs
            atomicAdd(&gvec[g * 128 + threadIdx.x], v);
        }
    }
}

// ---------------- Attention pooling (single block) ----------------

__global__ __launch_bounds__(256) void att_kernel(const float* __restrict__ gvec, const float* __restrict__ w1,
                                                  const float* __restrict__ w2, float* __restrict__ out) {
    __shared__ float sup[64][4];
    __shared__ float att[8][4];
    int t = threadIdx.x;
    int ah = t >> 2, gg = t & 3;  // 64*4 = 256 threads
    float d = 0.f;
    for (int k = 0; k < 128; ++k) d += w1[ah * 128 + k] * gvec[gg * 128 + k];
    sup[ah][gg] = tanhf(d);
    __syncthreads();
    if (t < 32) {
        int ne = t >> 2, g2 = t & 3;
        float sc = 0.f;
        for (int k = 0; k < 64; ++k) sc += w2[ne * 64 + k] * sup[k][g2];
        att[ne][g2] = sc;
    }
    __syncthreads();
    if (t < 8) {
        float m = fmaxf(fmaxf(att[t][0], att[t][1]), fmaxf(att[t][2], att[t][3]));
        float e0 = expf(att[t][0] - m), e1 = expf(att[t][1] - m);
        float e2 = expf(att[t][2] - m), e3 = expf(att[t][3] - m);
        float inv = 1.f / (e0 + e1 + e2 + e3);
        att[t][0] = e0 * inv; att[t][1] = e1 * inv; att[t][2] = e2 * inv; att[t][3] = e3 * inv;
    }
    __syncthreads();
    for (int o = t; o < 1024; o += 256) {
        int ne = o >> 7, dd = o & 127;
        float v = 0.f;
        for (int g2 = 0; g2 < 4; ++g2) v += att[ne][g2] * gvec[g2 * 128 + dd];
        out[o] = v;
    }
}

// ---------------- launch ----------------

extern "C" void kernel_launch(void* const* d_in, const int* in_sizes, int n_in,
                              void* d_out, int out_size, void* d_ws, size_t ws_size,
                              hipStream_t stream) {
    const float* x   = (const float*)d_in[0];
    const int*   ei  = (const int*)d_in[1];
    const float* Ws1 = (const float*)d_in[3];
    const float* bs1 = (const float*)d_in[4];
    const float* Ws2 = (const float*)d_in[5];
    const float* bs2 = (const float*)d_in[6];
    const float* lng = (const float*)d_in[7];
    const float* lnb = (const float*)d_in[8];
    const float* aw1 = (const float*)d_in[9];
    const float* aw2 = (const float*)d_in[10];

    char* ws = (char*)d_ws;
    float* A        = (float*)(ws);                      // 102,400,000 B
    float* B        = (float*)(ws + 102400000);          // 102,400,000 B
    int*   csr_src  = (int*)(ws + 204800000);            // 6,400,000 B
    int*   row_start= (int*)(ws + 211200000);            // 800,016 B (padded)
    int*   cursor   = (int*)(ws + 212000768);            // 800,000 B
    int*   deg      = (int*)(ws + 212800768);            // 800,000 B
    float* gvec     = (float*)(ws + 213600768);          // 2,048 B

    hipMemsetAsync(deg, 0, G * NN * sizeof(int), stream);
    hipMemsetAsync(gvec, 0, G * D * sizeof(float), stream);

    hist_kernel<<<(G * EE + 255) / 256, 256, 0, stream>>>(ei, deg);
    scan_kernel<<<G, 256, 0, stream>>>(deg, row_start, cursor);
    place_kernel<<<(G * EE + 255) / 256, 256, 0, stream>>>(ei, cursor, csr_src);

    const int nblocks = (G * NN) / 8;  // 25000
    for (int l = 0; l < 3; ++l) {
        const float* Xcur = (l == 0) ? x : A;
        agg_kernel<<<nblocks, 256, 0, stream>>>(Xcur, row_start, csr_src, B);
        mlp_kernel<<<nblocks, 256, 0, stream>>>(B, Xcur, A,
                                                Ws1 + l * D * D, bs1 + l * D,
                                                Ws2 + l * D * D, bs2 + l * D,
                                                lng + l * D, lnb + l * D,
                                                (l < 2) ? 1 : 0, (l == 2) ? 1 : 0, gvec);
    }
    att_kernel<<<1, 256, 0, stream>>>(gvec, aw1, aw2, (float*)d_out);
}

// Round 2
// 1153.063 us; speedup vs baseline: 2.6567x; 2.6567x over previous
//
#include <hip/hip_runtime.h>
#include <math.h>

#define G 4
#define NN 50000
#define EE 400000
#define D 128
#define LN_EPS 1e-5f
#define BPG 782  // blocks per graph in mlp (782*64 >= 50000)

typedef _Float16 f16;
typedef _Float16 f16x4 __attribute__((ext_vector_type(4)));
typedef _Float16 f16x8 __attribute__((ext_vector_type(8)));
typedef float f32x4 __attribute__((ext_vector_type(4)));

// ---------------- CSR build ----------------

__global__ __launch_bounds__(256) void hist_kernel(const int* __restrict__ ei, int* __restrict__ deg) {
    int idx = blockIdx.x * 256 + threadIdx.x;
    if (idx >= G * EE) return;
    int g = idx / EE, e = idx - g * EE;
    int dst = ei[g * 2 * EE + EE + e];
    atomicAdd(&deg[g * NN + dst], 1);
}

__global__ __launch_bounds__(256) void scan_kernel(const int* __restrict__ deg, int* __restrict__ row_start,
                                                   int* __restrict__ cursor) {
    int g = blockIdx.x, t = threadIdx.x;
    const int C = (NN + 255) / 256;
    __shared__ int sums[256];
    int start = t * C, end = min(start + C, NN);
    int s = 0;
    for (int i = start; i < end; ++i) s += deg[g * NN + i];
    sums[t] = s;
    __syncthreads();
    for (int off = 1; off < 256; off <<= 1) {
        int v = (t >= off) ? sums[t - off] : 0;
        __syncthreads();
        sums[t] += v;
        __syncthreads();
    }
    int run = (t == 0) ? 0 : sums[t - 1];
    for (int i = start; i < end; ++i) {
        row_start[g * (NN + 1) + i] = run;
        cursor[g * NN + i] = run;
        run += deg[g * NN + i];
    }
    if (t == 255) row_start[g * (NN + 1) + NN] = sums[255];
}

__global__ __launch_bounds__(256) void place_kernel(const int* __restrict__ ei, int* __restrict__ cursor,
                                                    int* __restrict__ csr_src) {
    int idx = blockIdx.x * 256 + threadIdx.x;
    if (idx >= G * EE) return;
    int g = idx / EE, e = idx - g * EE;
    int src = ei[g * 2 * EE + e];
    int dst = ei[g * 2 * EE + EE + e];
    int pos = atomicAdd(&cursor[g * NN + dst], 1);
    csr_src[g * EE + pos] = src;
}

// ---------------- dtype prep ----------------

__global__ __launch_bounds__(256) void cast_x_kernel(const float* __restrict__ x, f16* __restrict__ o) {
    int i = blockIdx.x * 256 + threadIdx.x;  // one float4 per thread
    float4 v = ((const float4*)x)[i];
    f16x4 h = {(f16)v.x, (f16)v.y, (f16)v.z, (f16)v.w};
    ((f16x4*)o)[i] = h;
}

// Wt[mat][n][k] = W[mat][k][n]  (fp16, transposed for MFMA B-operand)
__global__ __launch_bounds__(256) void cast_w_kernel(const float* __restrict__ Ws1, const float* __restrict__ Ws2,
                                                     f16* __restrict__ Wt) {
    int e = blockIdx.x * 256 + threadIdx.x;  // [0, 6*16384)
    int mat = e >> 14, r = (e >> 7) & 127, c = e & 127;
    const float* src = (mat < 3) ? (Ws1 + mat * 16384) : (Ws2 + (mat - 3) * 16384);
    Wt[e] = (f16)src[c * 128 + r];
}

// ---------------- Aggregation (fp16 storage, fp32 accumulate) ----------------

__global__ __launch_bounds__(256) void agg_kernel(const f16* __restrict__ X, const int* __restrict__ row_start,
                                                  const int* __restrict__ csr_src, f16* __restrict__ B) {
    int idx = blockIdx.x * 8 + (threadIdx.x >> 5);
    int lane = threadIdx.x & 31;
    int g = idx / NN, n = idx - g * NN;
    const f16x4* Xv = (const f16x4*)X;  // 8B units, 32 per 128-feat row
    f16x4 a = Xv[(long)idx * 32 + lane];
    float4 acc = {(float)a.x, (float)a.y, (float)a.z, (float)a.w};
    int s0 = row_start[g * (NN + 1) + n];
    int s1 = row_start[g * (NN + 1) + n + 1];
    const int* srcs = csr_src + g * EE;
    long gbase = (long)g * NN * 32;
    for (int k = s0; k < s1; ++k) {
        int sr = srcs[k];
        f16x4 v = Xv[gbase + (long)sr * 32 + lane];
        acc.x += (float)v.x; acc.y += (float)v.y; acc.z += (float)v.z; acc.w += (float)v.w;
    }
    f16x4 o = {(f16)acc.x, (f16)acc.y, (f16)acc.z, (f16)acc.w};
    ((f16x4*)B)[(long)idx * 32 + lane] = o;
}

// ---------------- Fused MFMA MLP + residual + LN (+ readout) ----------------
// block = 64 nodes of ONE graph; 4 waves, wave w owns rows [w*16, w*16+16)

__global__ __launch_bounds__(256) void mlp_kernel(
    const f16* __restrict__ Bagg, const f16* __restrict__ Xres, f16* __restrict__ Xout,
    const f16* __restrict__ W1t, const f16* __restrict__ W2t,
    const float* __restrict__ b1, const float* __restrict__ b2,
    const float* __restrict__ lng, const float* __restrict__ lnb,
    int has_res, int do_read, float* __restrict__ gvec) {
    __shared__ f16 A[64][136];
    __shared__ float colsum[128];

    int t = threadIdx.x;
    int g = blockIdx.x / BPG;
    int bb = blockIdx.x - g * BPG;
    int row0 = g * NN + bb * 64;
    int valid = min(64, NN - bb * 64);

    int w = t >> 6, l = t & 63, q = l >> 4, cl = l & 15;

    // ---- stage A tile (agg output, fp16) ----
    {
        int row = t >> 2, seg = t & 3;
        if (row < valid) {
            const f16x8* src = (const f16x8*)(Bagg + (long)(row0 + row) * 128 + seg * 32);
            f16x8 v0 = src[0], v1 = src[1], v2 = src[2], v3 = src[3];
            *(f16x8*)&A[row][seg * 32] = v0;
            *(f16x8*)&A[row][seg * 32 + 8] = v1;
            *(f16x8*)&A[row][seg * 32 + 16] = v2;
            *(f16x8*)&A[row][seg * 32 + 24] = v3;
        }
    }
    __syncthreads();

    int mrow = w * 16 + cl;

    // ---- GEMM1: y1 = relu(A @ W1 + b1) ----
    f32x4 acc[8];
#pragma unroll
    for (int ns = 0; ns < 8; ++ns) acc[ns] = (f32x4){0.f, 0.f, 0.f, 0.f};
#pragma unroll
    for (int kc = 0; kc < 4; ++kc) {
        f16x8 a = *(const f16x8*)&A[mrow][kc * 32 + q * 8];
#pragma unroll
        for (int ns = 0; ns < 8; ++ns) {
            f16x8 b = *(const f16x8*)(W1t + (ns * 16 + cl) * 128 + kc * 32 + q * 8);
            acc[ns] = __builtin_amdgcn_mfma_f32_16x16x32_f16(a, b, acc[ns], 0, 0, 0);
        }
    }
    __syncthreads();
#pragma unroll
    for (int ns = 0; ns < 8; ++ns) {
        float bv = b1[ns * 16 + cl];
#pragma unroll
        for (int r = 0; r < 4; ++r) {
            float v = fmaxf(acc[ns][r] + bv, 0.f);
            A[w * 16 + q * 4 + r][ns * 16 + cl] = (f16)v;  // wave-local rows
        }
    }
    __syncthreads();

    // ---- GEMM2: y2 = y1 @ W2 + b2 (+ residual) ----
    f32x4 acc2[8];
#pragma unroll
    for (int ns = 0; ns < 8; ++ns) acc2[ns] = (f32x4){0.f, 0.f, 0.f, 0.f};
#pragma unroll
    for (int kc = 0; kc < 4; ++kc) {
        f16x8 a = *(const f16x8*)&A[mrow][kc * 32 + q * 8];
#pragma unroll
        for (int ns = 0; ns < 8; ++ns) {
            f16x8 b = *(const f16x8*)(W2t + (ns * 16 + cl) * 128 + kc * 32 + q * 8);
            acc2[ns] = __builtin_amdgcn_mfma_f32_16x16x32_f16(a, b, acc2[ns], 0, 0, 0);
        }
    }

    float o[8][4];
    float gm[8], gb[8];
#pragma unroll
    for (int ns = 0; ns < 8; ++ns) {
        int col = ns * 16 + cl;
        float b2v = b2[col];
        gm[ns] = lng[col];
        gb[ns] = lnb[col];
#pragma unroll
        for (int r = 0; r < 4; ++r) o[ns][r] = acc2[ns][r] + b2v;
    }
    if (has_res) {
#pragma unroll
        for (int r = 0; r < 4; ++r) {
            int lr = w * 16 + q * 4 + r;
            if (lr < valid) {
                const f16* xr = Xres + (long)(row0 + lr) * 128;
#pragma unroll
                for (int ns = 0; ns < 8; ++ns) o[ns][r] += (float)xr[ns * 16 + cl];
            }
        }
    }

    // ---- LayerNorm per row (row = w*16+q*4+r, 16 lanes share a row) ----
#pragma unroll
    for (int r = 0; r < 4; ++r) {
        float s1 = 0.f, s2 = 0.f;
#pragma unroll
        for (int ns = 0; ns < 8; ++ns) { s1 += o[ns][r]; s2 += o[ns][r] * o[ns][r]; }
        s1 += __shfl_xor(s1, 1); s2 += __shfl_xor(s2, 1);
        s1 += __shfl_xor(s1, 2); s2 += __shfl_xor(s2, 2);
        s1 += __shfl_xor(s1, 4); s2 += __shfl_xor(s2, 4);
        s1 += __shfl_xor(s1, 8); s2 += __shfl_xor(s2, 8);
        float mean = s1 * (1.f / 128.f);
        float var = s2 * (1.f / 128.f) - mean * mean;
        float rstd = rsqrtf(var + LN_EPS);
#pragma unroll
        for (int ns = 0; ns < 8; ++ns) o[ns][r] = (o[ns][r] - mean) * rstd * gm[ns] + gb[ns];
    }

    // ---- write LN output to LDS (fp16), then coalesced store ----
#pragma unroll
    for (int ns = 0; ns < 8; ++ns)
#pragma unroll
        for (int r = 0; r < 4; ++r)
            A[w * 16 + q * 4 + r][ns * 16 + cl] = (f16)o[ns][r];
    __syncthreads();
    {
        int row = t >> 2, seg = t & 3;
        if (row < valid) {
            f16* dst = Xout + (long)(row0 + row) * 128 + seg * 32;
            *(f16x8*)(dst) = *(const f16x8*)&A[row][seg * 32];
            *(f16x8*)(dst + 8) = *(const f16x8*)&A[row][seg * 32 + 8];
            *(f16x8*)(dst + 16) = *(const f16x8*)&A[row][seg * 32 + 16];
            *(f16x8*)(dst + 24) = *(const f16x8*)&A[row][seg * 32 + 24];
        }
    }

    // ---- graph readout (last layer): gvec[g] += column sums ----
    if (do_read) {
        if (t < 128) colsum[t] = 0.f;
        __syncthreads();
#pragma unroll
        for (int ns = 0; ns < 8; ++ns) {
            float v = 0.f;
#pragma unroll
            for (int r = 0; r < 4; ++r) {
                int lr = w * 16 + q * 4 + r;
                if (lr < valid) v += o[ns][r];
            }
            v += __shfl_xor(v, 16);
            v += __shfl_xor(v, 32);
            if (l < 16) atomicAdd(&colsum[ns * 16 + cl], v);
        }
        __syncthreads();
        if (t < 128) atomicAdd(&gvec[g * 128 + t], colsum[t]);
    }
}

// ---------------- Attention pooling (single block) ----------------

__global__ __launch_bounds__(256) void att_kernel(const float* __restrict__ gvec, const float* __restrict__ w1,
                                                  const float* __restrict__ w2, float* __restrict__ out) {
    __shared__ float sup[64][4];
    __shared__ float att[8][4];
    int t = threadIdx.x;
    int ah = t >> 2, gg = t & 3;
    float d = 0.f;
    for (int k = 0; k < 128; ++k) d += w1[ah * 128 + k] * gvec[gg * 128 + k];
    sup[ah][gg] = tanhf(d);
    __syncthreads();
    if (t < 32) {
        int ne = t >> 2, g2 = t & 3;
        float sc = 0.f;
        for (int k = 0; k < 64; ++k) sc += w2[ne * 64 + k] * sup[k][g2];
        att[ne][g2] = sc;
    }
    __syncthreads();
    if (t < 8) {
        float m = fmaxf(fmaxf(att[t][0], att[t][1]), fmaxf(att[t][2], att[t][3]));
        float e0 = expf(att[t][0] - m), e1 = expf(att[t][1] - m);
        float e2 = expf(att[t][2] - m), e3 = expf(att[t][3] - m);
        float inv = 1.f / (e0 + e1 + e2 + e3);
        att[t][0] = e0 * inv; att[t][1] = e1 * inv; att[t][2] = e2 * inv; att[t][3] = e3 * inv;
    }
    __syncthreads();
    for (int o = t; o < 1024; o += 256) {
        int ne = o >> 7, dd = o & 127;
        float v = 0.f;
        for (int g2 = 0; g2 < 4; ++g2) v += att[ne][g2] * gvec[g2 * 128 + dd];
        out[o] = v;
    }
}

// ---------------- launch ----------------

extern "C" void kernel_launch(void* const* d_in, const int* in_sizes, int n_in,
                              void* d_out, int out_size, void* d_ws, size_t ws_size,
                              hipStream_t stream) {
    const float* x   = (const float*)d_in[0];
    const int*   ei  = (const int*)d_in[1];
    const float* Ws1 = (const float*)d_in[3];
    const float* bs1 = (const float*)d_in[4];
    const float* Ws2 = (const float*)d_in[5];
    const float* bs2 = (const float*)d_in[6];
    const float* lng = (const float*)d_in[7];
    const float* lnb = (const float*)d_in[8];
    const float* aw1 = (const float*)d_in[9];
    const float* aw2 = (const float*)d_in[10];

    char* ws = (char*)d_ws;
    f16*   XA       = (f16*)(ws);                       //  51,200,000 B
    f16*   XB       = (f16*)(ws + 51200000);            //  51,200,000 B
    f16*   BB       = (f16*)(ws + 102400000);           //  51,200,000 B
    int*   csr_src  = (int*)(ws + 153600000);           //   6,400,000 B
    int*   row_start= (int*)(ws + 160000000);           //     800,016 B (pad to 801,024)
    int*   cursor   = (int*)(ws + 160801024);           //     800,000 B
    int*   deg      = (int*)(ws + 161601024);           //     800,000 B
    f16*   Wt       = (f16*)(ws + 162401024);           //     196,608 B (6 x 128x128 fp16)
    float* gvec     = (float*)(ws + 162597632);         //       2,048 B

    hipMemsetAsync(deg, 0, G * NN * sizeof(int), stream);
    hipMemsetAsync(gvec, 0, G * D * sizeof(float), stream);

    hist_kernel<<<(G * EE + 255) / 256, 256, 0, stream>>>(ei, deg);
    scan_kernel<<<G, 256, 0, stream>>>(deg, row_start, cursor);
    place_kernel<<<(G * EE + 255) / 256, 256, 0, stream>>>(ei, cursor, csr_src);

    cast_x_kernel<<<(G * NN * D / 4) / 256, 256, 0, stream>>>(x, XA);
    cast_w_kernel<<<(6 * D * D) / 256, 256, 0, stream>>>(Ws1, Ws2, Wt);

    f16* Xcur = XA;
    f16* Xnxt = XB;
    for (int l = 0; l < 3; ++l) {
        agg_kernel<<<(G * NN) / 8, 256, 0, stream>>>(Xcur, row_start, csr_src, BB);
        mlp_kernel<<<G * BPG, 256, 0, stream>>>(BB, Xcur, Xnxt,
                                                Wt + l * D * D, Wt + (3 + l) * D * D,
                                                bs1 + l * D, bs2 + l * D,
                                                lng + l * D, lnb + l * D,
                                                (l < 2) ? 1 : 0, (l == 2) ? 1 : 0, gvec);
        f16* tmp = Xcur; Xcur = Xnxt; Xnxt = tmp;
    }
    att_kernel<<<1, 256, 0, stream>>>(gvec, aw1, aw2, (float*)d_out);
}

// Round 3
// 1024.754 us; speedup vs baseline: 2.9893x; 1.1252x over previous
//
#include <hip/hip_runtime.h>
#include <math.h>

#define G 4
#define NN 50000
#define EE 400000
#define D 128
#define LN_EPS 1e-5f
#define BPG 782  // blocks per graph (782*64 >= 50000)

typedef _Float16 f16;
typedef _Float16 f16x4 __attribute__((ext_vector_type(4)));
typedef _Float16 f16x8 __attribute__((ext_vector_type(8)));
typedef float f32x4 __attribute__((ext_vector_type(4)));

// ---------------- CSR build ----------------

__global__ __launch_bounds__(256) void hist_kernel(const int* __restrict__ ei, int* __restrict__ deg) {
    int idx = blockIdx.x * 256 + threadIdx.x;
    if (idx >= G * EE) return;
    int g = idx / EE, e = idx - g * EE;
    int dst = ei[g * 2 * EE + EE + e];
    atomicAdd(&deg[g * NN + dst], 1);
}

__global__ __launch_bounds__(256) void scan_kernel(const int* __restrict__ deg, int* __restrict__ row_start,
                                                   int* __restrict__ cursor) {
    int g = blockIdx.x, t = threadIdx.x;
    const int C = (NN + 255) / 256;
    __shared__ int sums[256];
    int start = t * C, end = min(start + C, NN);
    int s = 0;
    for (int i = start; i < end; ++i) s += deg[g * NN + i];
    sums[t] = s;
    __syncthreads();
    for (int off = 1; off < 256; off <<= 1) {
        int v = (t >= off) ? sums[t - off] : 0;
        __syncthreads();
        sums[t] += v;
        __syncthreads();
    }
    int run = (t == 0) ? 0 : sums[t - 1];
    for (int i = start; i < end; ++i) {
        row_start[g * (NN + 1) + i] = run;
        cursor[g * NN + i] = run;
        run += deg[g * NN + i];
    }
    if (t == 255) row_start[g * (NN + 1) + NN] = sums[255];
}

__global__ __launch_bounds__(256) void place_kernel(const int* __restrict__ ei, int* __restrict__ cursor,
                                                    int* __restrict__ csr_src) {
    int idx = blockIdx.x * 256 + threadIdx.x;
    if (idx >= G * EE) return;
    int g = idx / EE, e = idx - g * EE;
    int src = ei[g * 2 * EE + e];
    int dst = ei[g * 2 * EE + EE + e];
    int pos = atomicAdd(&cursor[g * NN + dst], 1);
    csr_src[g * EE + pos] = src;
}

// ---------------- dtype prep ----------------

__global__ __launch_bounds__(256) void cast_x_kernel(const float* __restrict__ x, f16* __restrict__ o) {
    int i = blockIdx.x * 256 + threadIdx.x;
    float4 v = ((const float4*)x)[i];
    f16x4 h = {(f16)v.x, (f16)v.y, (f16)v.z, (f16)v.w};
    ((f16x4*)o)[i] = h;
}

// Wt[mat][n][k] = W[mat][k][n]  (fp16, transposed for MFMA B-operand)
__global__ __launch_bounds__(256) void cast_w_kernel(const float* __restrict__ Ws1, const float* __restrict__ Ws2,
                                                     f16* __restrict__ Wt) {
    int e = blockIdx.x * 256 + threadIdx.x;
    int mat = e >> 14, r = (e >> 7) & 127, c = e & 127;
    const float* src = (mat < 3) ? (Ws1 + mat * 16384) : (Ws2 + (mat - 3) * 16384);
    Wt[e] = (f16)src[c * 128 + r];
}

// ---------------- Fused GIN layer: gather + MLP(MFMA) + residual + LN + readout ----------------
// block = 64 nodes of one graph; 256 threads = 4 waves.

__global__ __launch_bounds__(256) void gin_layer(
    const f16* __restrict__ Xin, f16* __restrict__ Xout,
    const int* __restrict__ row_start, const int* __restrict__ csr_src,
    const f16* __restrict__ W1t, const f16* __restrict__ W2t,
    const float* __restrict__ b1, const float* __restrict__ b2,
    const float* __restrict__ lng, const float* __restrict__ lnb,
    int has_res, int do_read, float* __restrict__ gvec)
{
    __shared__ f16 A[64][136];    // gathered h tile; reused for y1, then LN-output staging
    __shared__ f16 ID[64][136];   // identity (self) tile for residual
    __shared__ f16 WL[128][136];  // current weight matrix (B-operand rows)
    __shared__ float colsum[128];

    int t = threadIdx.x;
    int g = blockIdx.x / BPG, bb = blockIdx.x - g * BPG;
    int nrow0 = bb * 64;
    long row0 = (long)g * NN + nrow0;
    int valid = min(64, NN - nrow0);

    if (do_read && t < 128) colsum[t] = 0.f;

    // ---- prefetch W1 into registers (coalesced), written to LDS after gather ----
    f16x8 wtmp[8];
#pragma unroll
    for (int i = 0; i < 8; ++i)
        wtmp[i] = *(const f16x8*)(W1t + i * 2048 + t * 8);

    // ---- gather: 16 groups of 16 lanes, 4 rows each; f16x8 (16 B) per lane ----
    {
        int grp = t >> 4, lane = t & 15;
        const int* rs = row_start + g * (NN + 1);
        const int* srcs = csr_src + (long)g * EE;
        long gbase = (long)g * NN * 16;  // in f16x8 units (16 per row)
        const f16x8* Xv = (const f16x8*)Xin;
#pragma unroll
        for (int i = 0; i < 4; ++i) {
            int r = grp * 4 + i;
            if (r < valid) {
                int n = nrow0 + r;
                f16x8 self = Xv[(row0 + r) * 16 + lane];
                if (has_res) *(f16x8*)&ID[r][lane * 8] = self;
                float acc[8];
#pragma unroll
                for (int j = 0; j < 8; ++j) acc[j] = (float)self[j];
                int s0 = rs[n], s1 = rs[n + 1];
                int k = s0;
                for (; k + 1 < s1; k += 2) {
                    f16x8 v0 = Xv[gbase + (long)srcs[k] * 16 + lane];
                    f16x8 v1 = Xv[gbase + (long)srcs[k + 1] * 16 + lane];
#pragma unroll
                    for (int j = 0; j < 8; ++j) acc[j] += (float)v0[j] + (float)v1[j];
                }
                if (k < s1) {
                    f16x8 v0 = Xv[gbase + (long)srcs[k] * 16 + lane];
#pragma unroll
                    for (int j = 0; j < 8; ++j) acc[j] += (float)v0[j];
                }
                f16x8 o;
#pragma unroll
                for (int j = 0; j < 8; ++j) o[j] = (f16)acc[j];
                *(f16x8*)&A[r][lane * 8] = o;
            } else {
                f16x8 z = {0, 0, 0, 0, 0, 0, 0, 0};
                *(f16x8*)&A[r][lane * 8] = z;
            }
        }
    }

    // ---- commit W1 to LDS ----
    {
        int wr = t >> 4, wc = (t & 15) * 8;  // row block i*16 + (t>>4)
#pragma unroll
        for (int i = 0; i < 8; ++i)
            *(f16x8*)&WL[i * 16 + (t >> 4)][wc] = wtmp[i];
    }
    __syncthreads();  // B1: A, ID, WL ready

    int w = t >> 6, l = t & 63, q = l >> 4, cl = l & 15;
    int mrow = w * 16 + cl;

    // ---- GEMM1: y1 = relu(A @ W1 + b1) ----
    f32x4 acc[8];
#pragma unroll
    for (int ns = 0; ns < 8; ++ns) acc[ns] = (f32x4){0.f, 0.f, 0.f, 0.f};
#pragma unroll
    for (int kc = 0; kc < 4; ++kc) {
        f16x8 a = *(const f16x8*)&A[mrow][kc * 32 + q * 8];
#pragma unroll
        for (int ns = 0; ns < 8; ++ns) {
            f16x8 b = *(const f16x8*)&WL[ns * 16 + cl][kc * 32 + q * 8];
            acc[ns] = __builtin_amdgcn_mfma_f32_16x16x32_f16(a, b, acc[ns], 0, 0, 0);
        }
    }

    // prefetch W2 (global loads legal before barrier; drained by barrier's vmcnt)
#pragma unroll
    for (int i = 0; i < 8; ++i)
        wtmp[i] = *(const f16x8*)(W2t + i * 2048 + t * 8);

    __syncthreads();  // B2: all waves done reading WL(W1)

    // y1 -> A (wave-local rows, no cross-wave hazard); W2 -> LDS
#pragma unroll
    for (int ns = 0; ns < 8; ++ns) {
        float bv = b1[ns * 16 + cl];
#pragma unroll
        for (int r = 0; r < 4; ++r) {
            float v = fmaxf(acc[ns][r] + bv, 0.f);
            A[w * 16 + q * 4 + r][ns * 16 + cl] = (f16)v;
        }
    }
    {
        int wc = (t & 15) * 8;
#pragma unroll
        for (int i = 0; i < 8; ++i)
            *(f16x8*)&WL[i * 16 + (t >> 4)][wc] = wtmp[i];
    }
    __syncthreads();  // B3: y1, WL(W2) ready

    // ---- GEMM2: y2 = y1 @ W2 + b2 (+ identity) ----
    f32x4 acc2[8];
#pragma unroll
    for (int ns = 0; ns < 8; ++ns) acc2[ns] = (f32x4){0.f, 0.f, 0.f, 0.f};
#pragma unroll
    for (int kc = 0; kc < 4; ++kc) {
        f16x8 a = *(const f16x8*)&A[mrow][kc * 32 + q * 8];
#pragma unroll
        for (int ns = 0; ns < 8; ++ns) {
            f16x8 b = *(const f16x8*)&WL[ns * 16 + cl][kc * 32 + q * 8];
            acc2[ns] = __builtin_amdgcn_mfma_f32_16x16x32_f16(a, b, acc2[ns], 0, 0, 0);
        }
    }

    float o[8][4];
    float gm[8], gb[8];
#pragma unroll
    for (int ns = 0; ns < 8; ++ns) {
        int col = ns * 16 + cl;
        float b2v = b2[col];
        gm[ns] = lng[col];
        gb[ns] = lnb[col];
#pragma unroll
        for (int r = 0; r < 4; ++r) o[ns][r] = acc2[ns][r] + b2v;
    }
    if (has_res) {
#pragma unroll
        for (int r = 0; r < 4; ++r) {
            int lr = w * 16 + q * 4 + r;
#pragma unroll
            for (int ns = 0; ns < 8; ++ns) o[ns][r] += (float)ID[lr][ns * 16 + cl];
        }
    }

    // ---- LayerNorm per row (16 lanes of a q-group share a row) ----
#pragma unroll
    for (int r = 0; r < 4; ++r) {
        float s1 = 0.f, s2 = 0.f;
#pragma unroll
        for (int ns = 0; ns < 8; ++ns) { s1 += o[ns][r]; s2 += o[ns][r] * o[ns][r]; }
        s1 += __shfl_xor(s1, 1); s2 += __shfl_xor(s2, 1);
        s1 += __shfl_xor(s1, 2); s2 += __shfl_xor(s2, 2);
        s1 += __shfl_xor(s1, 4); s2 += __shfl_xor(s2, 4);
        s1 += __shfl_xor(s1, 8); s2 += __shfl_xor(s2, 8);
        float mean = s1 * (1.f / 128.f);
        float var = s2 * (1.f / 128.f) - mean * mean;
        float rstd = rsqrtf(var + LN_EPS);
#pragma unroll
        for (int ns = 0; ns < 8; ++ns) o[ns][r] = (o[ns][r] - mean) * rstd * gm[ns] + gb[ns];
    }

    if (!do_read) {
        // stage LN output in A (wave-local rows) for coalesced store
#pragma unroll
        for (int ns = 0; ns < 8; ++ns)
#pragma unroll
            for (int r = 0; r < 4; ++r)
                A[w * 16 + q * 4 + r][ns * 16 + cl] = (f16)o[ns][r];
        __syncthreads();  // B4
        int row = t >> 2, seg = t & 3;
        if (row < valid) {
            f16* dst = Xout + (row0 + row) * 128 + seg * 32;
            *(f16x8*)(dst) = *(const f16x8*)&A[row][seg * 32];
            *(f16x8*)(dst + 8) = *(const f16x8*)&A[row][seg * 32 + 8];
            *(f16x8*)(dst + 16) = *(const f16x8*)&A[row][seg * 32 + 16];
            *(f16x8*)(dst + 24) = *(const f16x8*)&A[row][seg * 32 + 24];
        }
    } else {
        // graph readout only (last layer): gvec[g] += column sums
#pragma unroll
        for (int ns = 0; ns < 8; ++ns) {
            float v = 0.f;
#pragma unroll
            for (int r = 0; r < 4; ++r) {
                int lr = w * 16 + q * 4 + r;
                if (lr < valid) v += o[ns][r];
            }
            v += __shfl_xor(v, 16);
            v += __shfl_xor(v, 32);
            if (l < 16) atomicAdd(&colsum[ns * 16 + cl], v);
        }
        __syncthreads();  // B4
        if (t < 128) atomicAdd(&gvec[g * 128 + t], colsum[t]);
    }
}

// ---------------- Attention pooling (single block) ----------------

__global__ __launch_bounds__(256) void att_kernel(const float* __restrict__ gvec, const float* __restrict__ w1,
                                                  const float* __restrict__ w2, float* __restrict__ out) {
    __shared__ float sup[64][4];
    __shared__ float att[8][4];
    int t = threadIdx.x;
    int ah = t >> 2, gg = t & 3;
    float d = 0.f;
    for (int k = 0; k < 128; ++k) d += w1[ah * 128 + k] * gvec[gg * 128 + k];
    sup[ah][gg] = tanhf(d);
    __syncthreads();
    if (t < 32) {
        int ne = t >> 2, g2 = t & 3;
        float sc = 0.f;
        for (int k = 0; k < 64; ++k) sc += w2[ne * 64 + k] * sup[k][g2];
        att[ne][g2] = sc;
    }
    __syncthreads();
    if (t < 8) {
        float m = fmaxf(fmaxf(att[t][0], att[t][1]), fmaxf(att[t][2], att[t][3]));
        float e0 = expf(att[t][0] - m), e1 = expf(att[t][1] - m);
        float e2 = expf(att[t][2] - m), e3 = expf(att[t][3] - m);
        float inv = 1.f / (e0 + e1 + e2 + e3);
        att[t][0] = e0 * inv; att[t][1] = e1 * inv; att[t][2] = e2 * inv; att[t][3] = e3 * inv;
    }
    __syncthreads();
    for (int o = t; o < 1024; o += 256) {
        int ne = o >> 7, dd = o & 127;
        float v = 0.f;
        for (int g2 = 0; g2 < 4; ++g2) v += att[ne][g2] * gvec[g2 * 128 + dd];
        out[o] = v;
    }
}

// ---------------- launch ----------------

extern "C" void kernel_launch(void* const* d_in, const int* in_sizes, int n_in,
                              void* d_out, int out_size, void* d_ws, size_t ws_size,
                              hipStream_t stream) {
    const float* x   = (const float*)d_in[0];
    const int*   ei  = (const int*)d_in[1];
    const float* Ws1 = (const float*)d_in[3];
    const float* bs1 = (const float*)d_in[4];
    const float* Ws2 = (const float*)d_in[5];
    const float* bs2 = (const float*)d_in[6];
    const float* lng = (const float*)d_in[7];
    const float* lnb = (const float*)d_in[8];
    const float* aw1 = (const float*)d_in[9];
    const float* aw2 = (const float*)d_in[10];

    char* ws = (char*)d_ws;
    f16*   XA       = (f16*)(ws);                      //  51,200,000 B
    f16*   XB       = (f16*)(ws + 51200000);           //  51,200,000 B
    int*   csr_src  = (int*)(ws + 102400000);          //   6,400,000 B
    int*   row_start= (int*)(ws + 108800000);          //     800,016 B (pad)
    int*   cursor   = (int*)(ws + 109600256);          //     800,000 B
    int*   deg      = (int*)(ws + 110400256);          //     800,000 B
    f16*   Wt       = (f16*)(ws + 111200256);          //     196,608 B
    float* gvec     = (float*)(ws + 111396864);        //       2,048 B

    hipMemsetAsync(deg, 0, G * NN * sizeof(int), stream);
    hipMemsetAsync(gvec, 0, G * D * sizeof(float), stream);

    hist_kernel<<<(G * EE + 255) / 256, 256, 0, stream>>>(ei, deg);
    scan_kernel<<<G, 256, 0, stream>>>(deg, row_start, cursor);
    place_kernel<<<(G * EE + 255) / 256, 256, 0, stream>>>(ei, cursor, csr_src);

    cast_x_kernel<<<(G * NN * D / 4) / 256, 256, 0, stream>>>(x, XA);
    cast_w_kernel<<<(6 * D * D) / 256, 256, 0, stream>>>(Ws1, Ws2, Wt);

    f16* Xcur = XA;
    f16* Xnxt = XB;
    for (int l = 0; l < 3; ++l) {
        gin_layer<<<G * BPG, 256, 0, stream>>>(Xcur, Xnxt, row_start, csr_src,
                                               Wt + l * D * D, Wt + (3 + l) * D * D,
                                               bs1 + l * D, bs2 + l * D,
                                               lng + l * D, lnb + l * D,
                                               (l < 2) ? 1 : 0, (l == 2) ? 1 : 0, gvec);
        f16* tmp = Xcur; Xcur = Xnxt; Xnxt = tmp;
    }
    att_kernel<<<1, 256, 0, stream>>>(gvec, aw1, aw2, (float*)d_out);
}